// Round 4
// baseline (679.582 us; speedup 1.0000x reference)
//
#include <hip/hip_runtime.h>
#include <math.h>

#define NN 50000
#define NE 800000
#define CD 128
#define NBIN 98          // bin workgroups (98*512 = 50176 >= NN)
#define NODES_PER 512
#define BT 1024          // threads per prep block

typedef __attribute__((ext_vector_type(8))) short short8;
typedef __attribute__((ext_vector_type(4))) float f32x4;

// ---------------- helpers ----------------

__device__ inline unsigned pack2bf(float lo, float hi) {
    unsigned a = __float_as_uint(lo), b = __float_as_uint(hi);
    a = (a + 0x7fffu + ((a >> 16) & 1u)) >> 16;
    b = (b + 0x7fffu + ((b >> 16) & 1u)) & 0xffff0000u;
    return a | b;
}

__device__ inline unsigned short f2bf(float f) {
    unsigned u = __float_as_uint(f);
    return (unsigned short)((u + 0x7fffu + ((u >> 16) & 1u)) >> 16);
}

// ---------------- fused prep: CSR build (blocks 0..97) + bf16 casts (rest) ----
// Bin blocks: each owns 512 dst nodes. Pass 1: LDS histogram over the full dst
// stream (L2-resident). LDS scan + one global atomicAdd allocates an exact
// compact csr region (no degree cap, no global scan chain). Pass 2: place src
// indices (ushort) via LDS cursors — sequential writes in a private ~16 KB
// region, killing scatter_k's 52 MB write-allocate traffic.
// Cast blocks: x -> bf16 (xb), W -> transposed bf16 wt[n][k].

__global__ __launch_bounds__(BT) void prep_k(const int* __restrict__ ei,
                                             const float* __restrict__ x,
                                             const float* __restrict__ W,
                                             int* __restrict__ gcur,
                                             int* __restrict__ offsets,
                                             unsigned short* __restrict__ counts16,
                                             unsigned short* __restrict__ csr,
                                             unsigned* __restrict__ xb,
                                             unsigned short* __restrict__ wt) {
    __shared__ int cnt[NODES_PER];
    __shared__ int scn[NODES_PER];
    __shared__ int sbase;
    int t = threadIdx.x;
    int b = blockIdx.x;

    if (b < NBIN) {                       // block-uniform branch: syncthreads legal
        int base = b * NODES_PER;
        const int* dstp = ei + NE;
        if (t < NODES_PER) cnt[t] = 0;
        __syncthreads();
        // pass 1: histogram
        for (int e = t; e < NE; e += BT) {
            unsigned r = (unsigned)(dstp[e] - base);
            if (r < NODES_PER) atomicAdd(&cnt[r], 1);
        }
        __syncthreads();
        // inclusive LDS scan of cnt -> scn
        if (t < NODES_PER) scn[t] = cnt[t];
        __syncthreads();
        for (int off = 1; off < NODES_PER; off <<= 1) {
            int v = 0;
            if (t < NODES_PER && t >= off) v = scn[t - off];
            __syncthreads();
            if (t < NODES_PER) scn[t] += v;
            __syncthreads();
        }
        if (t == 0) sbase = atomicAdd(gcur, scn[NODES_PER - 1]);
        __syncthreads();
        if (t < NODES_PER) {
            int o = sbase + scn[t] - cnt[t];  // exclusive offset for local node t
            int n = base + t;
            if (n < NN) { offsets[n] = o; counts16[n] = (unsigned short)cnt[t]; }
            cnt[t] = o;                       // repurpose as cursor
        }
        __syncthreads();
        // pass 2: place edges
        for (int e = t; e < NE; e += BT) {
            int d = dstp[e];
            unsigned r = (unsigned)(d - base);
            if (r < NODES_PER) {
                int p = atomicAdd(&cnt[r], 1);
                csr[p] = (unsigned short)ei[e];   // src < 50000 < 65536
            }
        }
    } else {
        int tid = (b - NBIN) * BT + t;
        if (tid < NN * CD / 4) {              // 1,600,000 float4s
            float4 v = ((const float4*)x)[tid];
            uint2 r;
            r.x = pack2bf(v.x, v.y);
            r.y = pack2bf(v.z, v.w);
            ((uint2*)xb)[tid] = r;
        } else {
            int i = tid - NN * CD / 4;
            if (i < 2 * CD * CD) {            // 32768 W elements
                int n = i >> 8, k = i & 255;
                wt[(size_t)n * 256 + k] = f2bf(W[(size_t)k * 128 + n]);
            }
        }
    }
}

// ---------------- per-node segment max (bf16 in, bf16 out) ----------------
// One wave per node. Quarter q = lane>>4 handles edge e+q; c = lane&15 covers
// 8 channels (16B). Indices preloaded coalesced + distributed via shfl.

__global__ __launch_bounds__(256) void gather_k(const unsigned* __restrict__ xb,
                                                const int* __restrict__ offsets,
                                                const unsigned short* __restrict__ counts16,
                                                const unsigned short* __restrict__ csr,
                                                unsigned* __restrict__ mdb) {
    int gid = blockIdx.x * 256 + threadIdx.x;
    int node = gid >> 6;
    if (node >= NN) return;
    int lane = threadIdx.x & 63;
    int q = lane >> 4;
    int c = lane & 15;
    int beg = offsets[node];
    int end = beg + (int)counts16[node];

    float m[8];
#pragma unroll
    for (int j = 0; j < 8; j++) m[j] = -INFINITY;

    for (int t0 = beg; t0 < end; t0 += 64) {
        int idxv = (t0 + lane < end) ? (int)csr[t0 + lane] : -1;
        int nT = min(64, end - t0);
        for (int e = 0; e < nT; e += 4) {
            int s = __shfl(idxv, e + q);
            if (s >= 0) {
                uint4 v = *(const uint4*)(xb + (size_t)s * 64 + c * 4);
                m[0] = fmaxf(m[0], __uint_as_float(v.x << 16));
                m[1] = fmaxf(m[1], __uint_as_float(v.x & 0xffff0000u));
                m[2] = fmaxf(m[2], __uint_as_float(v.y << 16));
                m[3] = fmaxf(m[3], __uint_as_float(v.y & 0xffff0000u));
                m[4] = fmaxf(m[4], __uint_as_float(v.z << 16));
                m[5] = fmaxf(m[5], __uint_as_float(v.z & 0xffff0000u));
                m[6] = fmaxf(m[6], __uint_as_float(v.w << 16));
                m[7] = fmaxf(m[7], __uint_as_float(v.w & 0xffff0000u));
            }
        }
    }
#pragma unroll
    for (int j = 0; j < 8; j++) {
        m[j] = fmaxf(m[j], __shfl_xor(m[j], 16));
        m[j] = fmaxf(m[j], __shfl_xor(m[j], 32));
    }
    if (lane < 16) {
        uint4 r = make_uint4(0u, 0u, 0u, 0u);
        if (end > beg) {
            uint4 xd = *(const uint4*)(xb + (size_t)node * 64 + c * 4);
            float d0 = m[0] - __uint_as_float(xd.x << 16);
            float d1 = m[1] - __uint_as_float(xd.x & 0xffff0000u);
            float d2 = m[2] - __uint_as_float(xd.y << 16);
            float d3 = m[3] - __uint_as_float(xd.y & 0xffff0000u);
            float d4 = m[4] - __uint_as_float(xd.z << 16);
            float d5 = m[5] - __uint_as_float(xd.z & 0xffff0000u);
            float d6 = m[6] - __uint_as_float(xd.w << 16);
            float d7 = m[7] - __uint_as_float(xd.w & 0xffff0000u);
            r.x = pack2bf(d0, d1);
            r.y = pack2bf(d2, d3);
            r.z = pack2bf(d4, d5);
            r.w = pack2bf(d6, d7);
        }
        *(uint4*)(mdb + (size_t)node * 64 + c * 4) = r;
    }
}

// ---------------- bf16 MFMA GEMM: out = [xb | mdb] @ Wt^T + bias ----------------
// Block = 4 waves, 64 rows x 128 cols. Wave w: rows r0+w*16..+15, all 128 cols
// via 8 col-tiles of 16x16x32 MFMA. A-frags direct from global (16B/lane),
// B-frags from transposed Wt[n][k] (L1/L2-resident, 64 KB total).

__global__ __launch_bounds__(256) void gemm_k(const short* __restrict__ xb,
                                              const short* __restrict__ mdb,
                                              const short* __restrict__ wt,
                                              const float* __restrict__ bias,
                                              float* __restrict__ out) {
    int t = threadIdx.x;
    int w = t >> 6, lane = t & 63;
    int m = lane & 15, g = lane >> 4;
    int r0 = blockIdx.x * 64 + w * 16;
    int row = r0 + m;
    bool rowok = row < NN;

    f32x4 acc[8];
#pragma unroll
    for (int ct = 0; ct < 8; ct++) {
        float bv = bias[ct * 16 + m];
        acc[ct] = (f32x4){bv, bv, bv, bv};
    }

#pragma unroll
    for (int kc = 0; kc < 8; kc++) {
        int k0 = kc * 32;
        short8 a = (short8){0, 0, 0, 0, 0, 0, 0, 0};
        if (rowok) {
            const short* A = (kc < 4) ? (xb + (size_t)row * 128 + k0 + g * 8)
                                      : (mdb + (size_t)row * 128 + (k0 - 128) + g * 8);
            a = *(const short8*)A;
        }
#pragma unroll
        for (int ct = 0; ct < 8; ct++) {
            short8 b = *(const short8*)(wt + (size_t)(ct * 16 + m) * 256 + k0 + g * 8);
            acc[ct] = __builtin_amdgcn_mfma_f32_16x16x32_bf16(a, b, acc[ct], 0, 0, 0);
        }
    }

#pragma unroll
    for (int ct = 0; ct < 8; ct++) {
#pragma unroll
        for (int i = 0; i < 4; i++) {
            int rr = r0 + g * 4 + i;
            if (rr < NN) out[(size_t)rr * 128 + ct * 16 + m] = acc[ct][i];
        }
    }
}

// ---------------- launch ----------------

extern "C" void kernel_launch(void* const* d_in, const int* in_sizes, int n_in,
                              void* d_out, int out_size, void* d_ws, size_t ws_size,
                              hipStream_t stream) {
    const float* x = (const float*)d_in[0];
    const int* ei = (const int*)d_in[1];     // (2, E): [0..E)=src, [E..2E)=dst
    const float* W = (const float*)d_in[2];  // (256, 128) row-major
    const float* bias = (const float*)d_in[3];
    float* out = (float*)d_out;

    // Workspace layout (ints). Total = 6,891,664 ints = 27.57 MB.
    int* wsi = (int*)d_ws;
    int* gcur = wsi;                                        // 16 ints (1 used)
    int* offsets = wsi + 16;                                // 50176 ints
    unsigned short* counts16 = (unsigned short*)(wsi + 50192);  // 50176 ush = 25088 ints
    unsigned short* csr = (unsigned short*)(wsi + 75280);       // 800000 ush = 400000 ints
    unsigned* xb  = (unsigned*)(wsi + 475280);              // 3,200,000 uints (16B aligned)
    unsigned* mdb = (unsigned*)(wsi + 3675280);             // 3,200,000 uints
    unsigned short* wt = (unsigned short*)(wsi + 6875280);  // 32768 ush = 16384 ints

    hipMemsetAsync(gcur, 0, 4, stream);

    int cast_blocks = (NN * CD / 4 + 2 * CD * CD + BT - 1) / BT;  // 1595
    prep_k<<<NBIN + cast_blocks, BT, 0, stream>>>(ei, x, W, gcur, offsets, counts16,
                                                  csr, xb, wt);
    gather_k<<<(NN * 64 + 255) / 256, 256, 0, stream>>>(xb, offsets, counts16, csr, mdb);
    gemm_k<<<(NN + 63) / 64, 256, 0, stream>>>((const short*)xb, (const short*)mdb,
                                               (const short*)wt, bias, out);
}

// Round 5
// 262.558 us; speedup vs baseline: 2.5883x; 2.5883x over previous
//
#include <hip/hip_runtime.h>
#include <math.h>

#define NN 50000
#define NE 800000
#define CD 128
#define LINKB 1600       // link-role blocks in prep2_k
#define CHUNK 64         // per-wave LDS index buffer (max expected degree ~40)

typedef __attribute__((ext_vector_type(8))) short short8;
typedef __attribute__((ext_vector_type(4))) float f32x4;

// ---------------- helpers ----------------

__device__ inline unsigned pack2bf(float lo, float hi) {
    unsigned a = __float_as_uint(lo), b = __float_as_uint(hi);
    a = (a + 0x7fffu + ((a >> 16) & 1u)) >> 16;
    b = (b + 0x7fffu + ((b >> 16) & 1u)) & 0xffff0000u;
    return a | b;
}

__device__ inline unsigned short f2bf(float f) {
    unsigned u = __float_as_uint(f);
    return (unsigned short)((u + 0x7fffu + ((u >> 16) & 1u)) >> 16);
}

// ---------------- fused prep: linked-list build (blocks 0..LINKB-1) + casts ----
// Link role: one pass over edges — old = atomicExch(head[dst], e); next[e] = old.
// Coalesced dst reads, coalesced full-line next writes (no write-allocate waste),
// atomicExch into 200 KB L2-resident head. No count/scan/scatter chain.
// Cast role: x -> bf16 (xb), W -> transposed bf16 wt[n][k].

__global__ __launch_bounds__(256) void prep2_k(const int* __restrict__ ei,
                                               const float* __restrict__ x,
                                               const float* __restrict__ W,
                                               int* __restrict__ head,
                                               int* __restrict__ next,
                                               unsigned* __restrict__ xb,
                                               unsigned short* __restrict__ wt) {
    int b = blockIdx.x;
    int t = threadIdx.x;
    if (b < LINKB) {
        for (int e = b * 256 + t; e < NE; e += LINKB * 256) {
            int d = ei[NE + e];
            int old = atomicExch(&head[d], e);
            next[e] = old;
        }
    } else {
        int tid = (b - LINKB) * 256 + t;
        if (tid < NN * CD / 4) {              // 1,600,000 float4s
            float4 v = ((const float4*)x)[tid];
            uint2 r;
            r.x = pack2bf(v.x, v.y);
            r.y = pack2bf(v.z, v.w);
            ((uint2*)xb)[tid] = r;
        } else {
            int i = tid - NN * CD / 4;
            if (i < 2 * CD * CD) {            // 32768 W elements
                int n = i >> 8, k = i & 255;
                wt[(size_t)n * 256 + k] = f2bf(W[(size_t)k * 128 + n]);
            }
        }
    }
}

// ---------------- per-node segment max (bf16 in, bf16 out) ----------------
// One wave per node. Chase the linked list (wave-uniform, latency hidden by
// other resident waves), collecting src ids into LDS; then process rows with
// 8 gathers in flight: quarter q handles entries e+q and e+q+4, c = lane&15
// covers 8 channels (16 B).

__global__ __launch_bounds__(256) void gather_k(const unsigned* __restrict__ xb,
                                                const int* __restrict__ head,
                                                const int* __restrict__ next,
                                                const int* __restrict__ srcp,
                                                unsigned* __restrict__ mdb) {
    __shared__ int idxs[4][CHUNK];
    int wv = threadIdx.x >> 6;
    int node = blockIdx.x * 4 + wv;
    if (node >= NN) return;
    int lane = threadIdx.x & 63;
    int q = lane >> 4;
    int c = lane & 15;

    int e = head[node];
    bool nonempty = (e >= 0);

    float m[8];
#pragma unroll
    for (int j = 0; j < 8; j++) m[j] = -INFINITY;

    do {
        // fill: wave-uniform chase, lane 0 resolves src ids into LDS
        int cnt = 0;
        while (e >= 0 && cnt < CHUNK) {
            if (lane == 0) idxs[wv][cnt] = srcp[e];
            e = next[e];
            cnt++;
        }
        // process: 8 rows in flight
        for (int e2 = 0; e2 < cnt; e2 += 8) {
            int s0 = (e2 + q < cnt) ? idxs[wv][e2 + q] : -1;
            int s1 = (e2 + 4 + q < cnt) ? idxs[wv][e2 + 4 + q] : -1;
            if (s0 >= 0) {
                uint4 v = *(const uint4*)(xb + (size_t)s0 * 64 + c * 4);
                m[0] = fmaxf(m[0], __uint_as_float(v.x << 16));
                m[1] = fmaxf(m[1], __uint_as_float(v.x & 0xffff0000u));
                m[2] = fmaxf(m[2], __uint_as_float(v.y << 16));
                m[3] = fmaxf(m[3], __uint_as_float(v.y & 0xffff0000u));
                m[4] = fmaxf(m[4], __uint_as_float(v.z << 16));
                m[5] = fmaxf(m[5], __uint_as_float(v.z & 0xffff0000u));
                m[6] = fmaxf(m[6], __uint_as_float(v.w << 16));
                m[7] = fmaxf(m[7], __uint_as_float(v.w & 0xffff0000u));
            }
            if (s1 >= 0) {
                uint4 v = *(const uint4*)(xb + (size_t)s1 * 64 + c * 4);
                m[0] = fmaxf(m[0], __uint_as_float(v.x << 16));
                m[1] = fmaxf(m[1], __uint_as_float(v.x & 0xffff0000u));
                m[2] = fmaxf(m[2], __uint_as_float(v.y << 16));
                m[3] = fmaxf(m[3], __uint_as_float(v.y & 0xffff0000u));
                m[4] = fmaxf(m[4], __uint_as_float(v.z << 16));
                m[5] = fmaxf(m[5], __uint_as_float(v.z & 0xffff0000u));
                m[6] = fmaxf(m[6], __uint_as_float(v.w << 16));
                m[7] = fmaxf(m[7], __uint_as_float(v.w & 0xffff0000u));
            }
        }
    } while (e >= 0);

#pragma unroll
    for (int j = 0; j < 8; j++) {
        m[j] = fmaxf(m[j], __shfl_xor(m[j], 16));
        m[j] = fmaxf(m[j], __shfl_xor(m[j], 32));
    }
    if (lane < 16) {
        uint4 r = make_uint4(0u, 0u, 0u, 0u);
        if (nonempty) {
            uint4 xd = *(const uint4*)(xb + (size_t)node * 64 + c * 4);
            float d0 = m[0] - __uint_as_float(xd.x << 16);
            float d1 = m[1] - __uint_as_float(xd.x & 0xffff0000u);
            float d2 = m[2] - __uint_as_float(xd.y << 16);
            float d3 = m[3] - __uint_as_float(xd.y & 0xffff0000u);
            float d4 = m[4] - __uint_as_float(xd.z << 16);
            float d5 = m[5] - __uint_as_float(xd.z & 0xffff0000u);
            float d6 = m[6] - __uint_as_float(xd.w << 16);
            float d7 = m[7] - __uint_as_float(xd.w & 0xffff0000u);
            r.x = pack2bf(d0, d1);
            r.y = pack2bf(d2, d3);
            r.z = pack2bf(d4, d5);
            r.w = pack2bf(d6, d7);
        }
        *(uint4*)(mdb + (size_t)node * 64 + c * 4) = r;
    }
}

// ---------------- bf16 MFMA GEMM: out = [xb | mdb] @ Wt^T + bias ----------------
// Block = 4 waves, 64 rows x 128 cols. Wave w: rows r0+w*16..+15, all 128 cols
// via 8 col-tiles of 16x16x32 MFMA. A-frags direct from global (16B/lane),
// B-frags from transposed Wt[n][k] (L1/L2-resident, 64 KB total).

__global__ __launch_bounds__(256) void gemm_k(const short* __restrict__ xb,
                                              const short* __restrict__ mdb,
                                              const short* __restrict__ wt,
                                              const float* __restrict__ bias,
                                              float* __restrict__ out) {
    int t = threadIdx.x;
    int w = t >> 6, lane = t & 63;
    int m = lane & 15, g = lane >> 4;
    int r0 = blockIdx.x * 64 + w * 16;
    int row = r0 + m;
    bool rowok = row < NN;

    f32x4 acc[8];
#pragma unroll
    for (int ct = 0; ct < 8; ct++) {
        float bv = bias[ct * 16 + m];
        acc[ct] = (f32x4){bv, bv, bv, bv};
    }

#pragma unroll
    for (int kc = 0; kc < 8; kc++) {
        int k0 = kc * 32;
        short8 a = (short8){0, 0, 0, 0, 0, 0, 0, 0};
        if (rowok) {
            const short* A = (kc < 4) ? (xb + (size_t)row * 128 + k0 + g * 8)
                                      : (mdb + (size_t)row * 128 + (k0 - 128) + g * 8);
            a = *(const short8*)A;
        }
#pragma unroll
        for (int ct = 0; ct < 8; ct++) {
            short8 b = *(const short8*)(wt + (size_t)(ct * 16 + m) * 256 + k0 + g * 8);
            acc[ct] = __builtin_amdgcn_mfma_f32_16x16x32_bf16(a, b, acc[ct], 0, 0, 0);
        }
    }

#pragma unroll
    for (int ct = 0; ct < 8; ct++) {
#pragma unroll
        for (int i = 0; i < 4; i++) {
            int rr = r0 + g * 4 + i;
            if (rr < NN) out[(size_t)rr * 128 + ct * 16 + m] = acc[ct][i];
        }
    }
}

// ---------------- launch ----------------

extern "C" void kernel_launch(void* const* d_in, const int* in_sizes, int n_in,
                              void* d_out, int out_size, void* d_ws, size_t ws_size,
                              hipStream_t stream) {
    const float* x = (const float*)d_in[0];
    const int* ei = (const int*)d_in[1];     // (2, E): [0..E)=src, [E..2E)=dst
    const float* W = (const float*)d_in[2];  // (256, 128) row-major
    const float* bias = (const float*)d_in[3];
    float* out = (float*)d_out;

    // Workspace layout (ints). Total = 7,266,432 ints = 29.07 MB.
    int* wsi = (int*)d_ws;
    int* head = wsi;                                        // 50048 ints
    int* next = wsi + 50048;                                // 800000 ints
    unsigned* xb  = (unsigned*)(wsi + 850048);              // 3,200,000 uints (16B aligned)
    unsigned* mdb = (unsigned*)(wsi + 4050048);             // 3,200,000 uints
    unsigned short* wt = (unsigned short*)(wsi + 7250048);  // 32768 ush = 16384 ints

    hipMemsetAsync(head, 0xFF, NN * sizeof(int), stream);   // head = -1

    int cast_blocks = (NN * CD / 4 + 2 * CD * CD + 255) / 256;  // 6379
    prep2_k<<<LINKB + cast_blocks, 256, 0, stream>>>(ei, x, W, head, next, xb, wt);
    gather_k<<<(NN + 3) / 4, 256, 0, stream>>>(xb, head, next, ei, mdb);
    gemm_k<<<(NN + 63) / 64, 256, 0, stream>>>((const short*)xb, (const short*)mdb,
                                               (const short*)wt, bias, out);
}

// Round 6
// 197.435 us; speedup vs baseline: 3.4420x; 1.3298x over previous
//
#include <hip/hip_runtime.h>
#include <math.h>

#define NN 50000
#define NE 800000
#define CD 128
#define LINKB 1600       // link-role blocks in prep2_k

typedef __attribute__((ext_vector_type(8))) short short8;
typedef __attribute__((ext_vector_type(4))) float f32x4;

// ---------------- helpers ----------------

__device__ inline unsigned pack2bf(float lo, float hi) {
    unsigned a = __float_as_uint(lo), b = __float_as_uint(hi);
    a = (a + 0x7fffu + ((a >> 16) & 1u)) >> 16;
    b = (b + 0x7fffu + ((b >> 16) & 1u)) & 0xffff0000u;
    return a | b;
}

__device__ inline unsigned short f2bf(float f) {
    unsigned u = __float_as_uint(f);
    return (unsigned short)((u + 0x7fffu + ((u >> 16) & 1u)) >> 16);
}

__device__ inline void fmax8(float* m, uint4 v) {
    m[0] = fmaxf(m[0], __uint_as_float(v.x << 16));
    m[1] = fmaxf(m[1], __uint_as_float(v.x & 0xffff0000u));
    m[2] = fmaxf(m[2], __uint_as_float(v.y << 16));
    m[3] = fmaxf(m[3], __uint_as_float(v.y & 0xffff0000u));
    m[4] = fmaxf(m[4], __uint_as_float(v.z << 16));
    m[5] = fmaxf(m[5], __uint_as_float(v.z & 0xffff0000u));
    m[6] = fmaxf(m[6], __uint_as_float(v.w << 16));
    m[7] = fmaxf(m[7], __uint_as_float(v.w & 0xffff0000u));
}

// ---------------- fused prep: linked-list build (blocks 0..LINKB-1) + casts ----
// Link role: one pass — old = atomicExch(head[dst], e); next[e] = old.
// Coalesced dst reads, coalesced next writes, atomics into 200 KB L2-resident head.
// Cast role: x -> bf16 (xb), W -> transposed bf16 wt[n][k].

__global__ __launch_bounds__(256) void prep2_k(const int* __restrict__ ei,
                                               const float* __restrict__ x,
                                               const float* __restrict__ W,
                                               int* __restrict__ head,
                                               int* __restrict__ next,
                                               unsigned* __restrict__ xb,
                                               unsigned short* __restrict__ wt) {
    int b = blockIdx.x;
    int t = threadIdx.x;
    if (b < LINKB) {
        for (int e = b * 256 + t; e < NE; e += LINKB * 256) {
            int d = ei[NE + e];
            int old = atomicExch(&head[d], e);
            next[e] = old;
        }
    } else {
        int tid = (b - LINKB) * 256 + t;
        if (tid < NN * CD / 4) {              // 1,600,000 float4s
            float4 v = ((const float4*)x)[tid];
            uint2 r;
            r.x = pack2bf(v.x, v.y);
            r.y = pack2bf(v.z, v.w);
            ((uint2*)xb)[tid] = r;
        } else {
            int i = tid - NN * CD / 4;
            if (i < 2 * CD * CD) {            // 32768 W elements
                int n = i >> 8, k = i & 255;
                wt[(size_t)n * 256 + k] = f2bf(W[(size_t)k * 128 + n]);
            }
        }
    }
}

// ---------------- fused gather + GEMM: one block = 64 output rows -------------
// Phase 0: 64 threads chase 64 node chains in parallel -> LDS index lists.
// Phase 1: each 16-lane quarter owns one node; 4 rows in flight/quarter
//          (16/wave); per-lane channels c*8..c*8+7; maxdiff bf16 -> LDS A-tile.
// Phase 2: round-3 MFMA GEMM; maxdiff A-half comes from LDS, x-half from global.

__global__ __launch_bounds__(256) void fused_k(const unsigned* __restrict__ xb,
                                               const int* __restrict__ head,
                                               const int* __restrict__ next,
                                               const int* __restrict__ srcp,
                                               const short* __restrict__ wt,
                                               const float* __restrict__ bias,
                                               float* __restrict__ out) {
    __shared__ unsigned short idx[64][68];   // 64 entries + cnt at [64]; pitch 68 (8B align, conflict-free)
    __shared__ int ovf[64];                  // overflow chain head (-1 normally)
    __shared__ unsigned short amx[64][136];  // maxdiff bf16 A-tile, padded pitch

    int t = threadIdx.x;
    int nbase = blockIdx.x * 64;

    // ---- phase 0: parallel chain chase (threads 0..63, 64 chains in flight) ----
    if (t < 64) {
        int node = nbase + t;
        int e = (node < NN) ? head[node] : -1;
        int cnt = 0;
        while (e >= 0 && cnt < 64) {
            idx[t][cnt] = (unsigned short)srcp[e];
            e = next[e];
            cnt++;
        }
        idx[t][64] = (unsigned short)cnt;
        ovf[t] = e;                          // >=0 only if degree > 64 (never, in practice)
    }
    __syncthreads();

    // ---- phase 1: segment max, one node per 16-lane quarter ----
    int w = t >> 6, lane = t & 63;
    int q = lane >> 4, c = lane & 15;
#pragma unroll 1
    for (int j = 0; j < 4; j++) {
        int ln = w * 16 + j * 4 + q;         // local node for this quarter
        int node = nbase + ln;
        int cnt = idx[ln][64];
        float m[8];
#pragma unroll
        for (int i = 0; i < 8; i++) m[i] = -INFINITY;

        for (int base = 0; base < cnt; base += 4) {
            uint2 packed = *(const uint2*)&idx[ln][base];   // 4 entries, 8B aligned
            int s0 = (int)(packed.x & 0xffffu);
            int s1 = (int)(packed.x >> 16);
            int s2 = (int)(packed.y & 0xffffu);
            int s3 = (int)(packed.y >> 16);
            if (base + 0 < cnt) fmax8(m, *(const uint4*)(xb + (size_t)s0 * 64 + c * 4));
            if (base + 1 < cnt) fmax8(m, *(const uint4*)(xb + (size_t)s1 * 64 + c * 4));
            if (base + 2 < cnt) fmax8(m, *(const uint4*)(xb + (size_t)s2 * 64 + c * 4));
            if (base + 3 < cnt) fmax8(m, *(const uint4*)(xb + (size_t)s3 * 64 + c * 4));
        }
        // overflow fallback (degree > 64): wave-divergent per-quarter chain walk
        int e = ovf[ln];
        while (e >= 0) {
            int s = srcp[e];
            fmax8(m, *(const uint4*)(xb + (size_t)s * 64 + c * 4));
            e = next[e];
        }
        uint4 r = make_uint4(0u, 0u, 0u, 0u);
        if (cnt > 0) {                        // node has incoming edges (=> node < NN)
            uint4 xd = *(const uint4*)(xb + (size_t)node * 64 + c * 4);
            float d0 = m[0] - __uint_as_float(xd.x << 16);
            float d1 = m[1] - __uint_as_float(xd.x & 0xffff0000u);
            float d2 = m[2] - __uint_as_float(xd.y << 16);
            float d3 = m[3] - __uint_as_float(xd.y & 0xffff0000u);
            float d4 = m[4] - __uint_as_float(xd.z << 16);
            float d5 = m[5] - __uint_as_float(xd.z & 0xffff0000u);
            float d6 = m[6] - __uint_as_float(xd.w << 16);
            float d7 = m[7] - __uint_as_float(xd.w & 0xffff0000u);
            r.x = pack2bf(d0, d1);
            r.y = pack2bf(d2, d3);
            r.z = pack2bf(d4, d5);
            r.w = pack2bf(d6, d7);
        }
        *(uint4*)&amx[ln][c * 8] = r;         // 16B, bank-clean (2-way max)
    }
    __syncthreads();

    // ---- phase 2: MFMA GEMM (identical math to the verified round-3 gemm_k) ----
    int mm = lane & 15, g = lane >> 4;
    int r0 = nbase + w * 16;
    int row = r0 + mm;
    bool rowok = row < NN;

    f32x4 acc[8];
#pragma unroll
    for (int ct = 0; ct < 8; ct++) {
        float bv = bias[ct * 16 + mm];
        acc[ct] = (f32x4){bv, bv, bv, bv};
    }

    const short* xbs = (const short*)xb;
#pragma unroll
    for (int kc = 0; kc < 8; kc++) {
        int k0 = kc * 32;
        short8 a;
        if (kc < 4) {
            a = (short8){0, 0, 0, 0, 0, 0, 0, 0};
            if (rowok) a = *(const short8*)(xbs + (size_t)row * 128 + k0 + g * 8);
        } else {
            a = *(const short8*)&amx[w * 16 + mm][(k0 - 128) + g * 8];
        }
#pragma unroll
        for (int ct = 0; ct < 8; ct++) {
            short8 b = *(const short8*)(wt + (size_t)(ct * 16 + mm) * 256 + k0 + g * 8);
            acc[ct] = __builtin_amdgcn_mfma_f32_16x16x32_bf16(a, b, acc[ct], 0, 0, 0);
        }
    }

#pragma unroll
    for (int ct = 0; ct < 8; ct++) {
#pragma unroll
        for (int i = 0; i < 4; i++) {
            int rr = r0 + g * 4 + i;
            if (rr < NN) out[(size_t)rr * 128 + ct * 16 + mm] = acc[ct][i];
        }
    }
}

// ---------------- launch ----------------

extern "C" void kernel_launch(void* const* d_in, const int* in_sizes, int n_in,
                              void* d_out, int out_size, void* d_ws, size_t ws_size,
                              hipStream_t stream) {
    const float* x = (const float*)d_in[0];
    const int* ei = (const int*)d_in[1];     // (2, E): [0..E)=src, [E..2E)=dst
    const float* W = (const float*)d_in[2];  // (256, 128) row-major
    const float* bias = (const float*)d_in[3];
    float* out = (float*)d_out;

    // Workspace layout (ints). Total = 4,066,432 ints = 16.27 MB.
    int* wsi = (int*)d_ws;
    int* head = wsi;                                        // 50048 ints
    int* next = wsi + 50048;                                // 800000 ints
    unsigned* xb  = (unsigned*)(wsi + 850048);              // 3,200,000 uints (16B aligned)
    unsigned short* wt = (unsigned short*)(wsi + 4050048);  // 32768 ush = 16384 ints

    hipMemsetAsync(head, 0xFF, NN * sizeof(int), stream);   // head = -1

    int cast_blocks = (NN * CD / 4 + 2 * CD * CD + 255) / 256;  // 6379
    prep2_k<<<LINKB + cast_blocks, 256, 0, stream>>>(ei, x, W, head, next, xb, wt);
    fused_k<<<(NN + 63) / 64, 256, 0, stream>>>(xb, head, next, ei, (const short*)wt,
                                                bias, out);
}

// Round 7
// 186.510 us; speedup vs baseline: 3.6437x; 1.0586x over previous
//
#include <hip/hip_runtime.h>
#include <math.h>

#define NN 50000
#define NE 800000
#define CD 128
#define PB 3200          // prep blocks (grid-stride)

typedef __attribute__((ext_vector_type(8))) short short8;
typedef __attribute__((ext_vector_type(4))) float f32x4;
typedef unsigned long long ull;

// ---------------- helpers ----------------

__device__ inline unsigned pack2bf(float lo, float hi) {
    unsigned a = __float_as_uint(lo), b = __float_as_uint(hi);
    a = (a + 0x7fffu + ((a >> 16) & 1u)) >> 16;
    b = (b + 0x7fffu + ((b >> 16) & 1u)) & 0xffff0000u;
    return a | b;
}

__device__ inline unsigned short f2bf(float f) {
    unsigned u = __float_as_uint(f);
    return (unsigned short)((u + 0x7fffu + ((u >> 16) & 1u)) >> 16);
}

__device__ inline void fmax8(float* m, uint4 v) {
    m[0] = fmaxf(m[0], __uint_as_float(v.x << 16));
    m[1] = fmaxf(m[1], __uint_as_float(v.x & 0xffff0000u));
    m[2] = fmaxf(m[2], __uint_as_float(v.y << 16));
    m[3] = fmaxf(m[3], __uint_as_float(v.y & 0xffff0000u));
    m[4] = fmaxf(m[4], __uint_as_float(v.z << 16));
    m[5] = fmaxf(m[5], __uint_as_float(v.z & 0xffff0000u));
    m[6] = fmaxf(m[6], __uint_as_float(v.w << 16));
    m[7] = fmaxf(m[7], __uint_as_float(v.w & 0xffff0000u));
}

// ---------------- prep: linked list (src packed into next) + bf16 casts -------
// Every block does BOTH roles via grid-stride, parity-staggered so atomic
// round-trips overlap with streaming cast traffic on every CU from t=0.
// nxt2[e] = (src << 32) | old_head  — one 8B load per chase hop downstream.

__global__ __launch_bounds__(256) void prep3_k(const int* __restrict__ ei,
                                               const float* __restrict__ x,
                                               const float* __restrict__ W,
                                               int* __restrict__ head,
                                               ull* __restrict__ nxt2,
                                               unsigned* __restrict__ xb,
                                               unsigned short* __restrict__ wt) {
    int tid0 = blockIdx.x * 256 + threadIdx.x;
    int phase = blockIdx.x & 1;

    for (int p = 0; p < 2; p++) {
        if ((p ^ phase) == 0) {
            // link slice
            for (int e = tid0; e < NE; e += PB * 256) {
                int d = ei[NE + e];
                unsigned s = (unsigned)ei[e];
                int old = atomicExch(&head[d], e);
                nxt2[e] = ((ull)s << 32) | (unsigned)old;
            }
        } else {
            // x -> bf16 slice
            for (int i = tid0; i < NN * CD / 4; i += PB * 256) {
                float4 v = ((const float4*)x)[i];
                uint2 r;
                r.x = pack2bf(v.x, v.y);
                r.y = pack2bf(v.z, v.w);
                ((uint2*)xb)[i] = r;
            }
        }
    }
    // W -> transposed bf16 wt[n][k]
    for (int i = tid0; i < 2 * CD * CD; i += PB * 256) {
        int n = i >> 8, k = i & 255;
        wt[(size_t)n * 256 + k] = f2bf(W[(size_t)k * 128 + n]);
    }
}

// ---------------- fused gather + GEMM: one block = 64 output rows, 8 waves ----
// Phase 0: 64 threads chase 64 chains in parallel (1×8B load/hop) -> LDS lists.
// Phase 1: 8 waves × 4 quarters; each quarter owns a node with 8 row-loads in
//          flight (fast path for full groups); maxdiff bf16 -> LDS A-tile.
// Phase 2: MFMA GEMM, wave w = row-tile (w&3) × col-half (w>>2).

__global__ __launch_bounds__(512) void fused_k(const unsigned* __restrict__ xb,
                                               const int* __restrict__ head,
                                               const ull* __restrict__ nxt2,
                                               const short* __restrict__ wt,
                                               const float* __restrict__ bias,
                                               float* __restrict__ out) {
    __shared__ unsigned short idx[64][72];   // 64 entries, pitch 72 ush = 144 B (16B-aligned rows)
    __shared__ unsigned short deg[64];
    __shared__ int ovf[64];                  // overflow chain cursor (-1 normally)
    __shared__ unsigned short amx[64][136];  // maxdiff bf16 A-tile, pitch 272 B

    int t = threadIdx.x;
    int nbase = blockIdx.x * 64;

    // ---- phase 0 ----
    if (t < 64) {
        int node = nbase + t;
        int e = (node < NN) ? head[node] : -1;
        int cnt = 0;
        while (e >= 0 && cnt < 64) {
            ull v = nxt2[e];
            idx[t][cnt] = (unsigned short)(v >> 32);
            e = (int)(unsigned)(v & 0xffffffffu);
            cnt++;
        }
        deg[t] = (unsigned short)cnt;
        ovf[t] = e;
    }
    __syncthreads();

    // ---- phase 1 ----
    int w = t >> 6, lane = t & 63;
    int q = lane >> 4, c = lane & 15;
#pragma unroll 1
    for (int j = 0; j < 2; j++) {
        int ln = w * 8 + j * 4 + q;
        int node = nbase + ln;
        int cnt = deg[ln];
        float m[8];
#pragma unroll
        for (int i = 0; i < 8; i++) m[i] = -INFINITY;

        for (int base = 0; base < cnt; base += 8) {
            uint4 pk = *(const uint4*)&idx[ln][base];
            int s0 = (int)(pk.x & 0xffffu), s1 = (int)(pk.x >> 16);
            int s2 = (int)(pk.y & 0xffffu), s3 = (int)(pk.y >> 16);
            int s4 = (int)(pk.z & 0xffffu), s5 = (int)(pk.z >> 16);
            int s6 = (int)(pk.w & 0xffffu), s7 = (int)(pk.w >> 16);
            if (base + 8 <= cnt) {            // fast path: 8 loads in flight
                fmax8(m, *(const uint4*)(xb + (size_t)s0 * 64 + c * 4));
                fmax8(m, *(const uint4*)(xb + (size_t)s1 * 64 + c * 4));
                fmax8(m, *(const uint4*)(xb + (size_t)s2 * 64 + c * 4));
                fmax8(m, *(const uint4*)(xb + (size_t)s3 * 64 + c * 4));
                fmax8(m, *(const uint4*)(xb + (size_t)s4 * 64 + c * 4));
                fmax8(m, *(const uint4*)(xb + (size_t)s5 * 64 + c * 4));
                fmax8(m, *(const uint4*)(xb + (size_t)s6 * 64 + c * 4));
                fmax8(m, *(const uint4*)(xb + (size_t)s7 * 64 + c * 4));
            } else {
                if (base + 0 < cnt) fmax8(m, *(const uint4*)(xb + (size_t)s0 * 64 + c * 4));
                if (base + 1 < cnt) fmax8(m, *(const uint4*)(xb + (size_t)s1 * 64 + c * 4));
                if (base + 2 < cnt) fmax8(m, *(const uint4*)(xb + (size_t)s2 * 64 + c * 4));
                if (base + 3 < cnt) fmax8(m, *(const uint4*)(xb + (size_t)s3 * 64 + c * 4));
                if (base + 4 < cnt) fmax8(m, *(const uint4*)(xb + (size_t)s4 * 64 + c * 4));
                if (base + 5 < cnt) fmax8(m, *(const uint4*)(xb + (size_t)s5 * 64 + c * 4));
                if (base + 6 < cnt) fmax8(m, *(const uint4*)(xb + (size_t)s6 * 64 + c * 4));
                if (base + 7 < cnt) fmax8(m, *(const uint4*)(xb + (size_t)s7 * 64 + c * 4));
            }
        }
        // overflow fallback (degree > 64): practically never taken
        int e = ovf[ln];
        while (e >= 0) {
            ull v = nxt2[e];
            int s = (int)(v >> 32);
            fmax8(m, *(const uint4*)(xb + (size_t)s * 64 + c * 4));
            e = (int)(unsigned)(v & 0xffffffffu);
        }
        uint4 r = make_uint4(0u, 0u, 0u, 0u);
        if (cnt > 0) {                        // implies node < NN
            uint4 xd = *(const uint4*)(xb + (size_t)node * 64 + c * 4);
            float d0 = m[0] - __uint_as_float(xd.x << 16);
            float d1 = m[1] - __uint_as_float(xd.x & 0xffff0000u);
            float d2 = m[2] - __uint_as_float(xd.y << 16);
            float d3 = m[3] - __uint_as_float(xd.y & 0xffff0000u);
            float d4 = m[4] - __uint_as_float(xd.z << 16);
            float d5 = m[5] - __uint_as_float(xd.z & 0xffff0000u);
            float d6 = m[6] - __uint_as_float(xd.w << 16);
            float d7 = m[7] - __uint_as_float(xd.w & 0xffff0000u);
            r.x = pack2bf(d0, d1);
            r.y = pack2bf(d2, d3);
            r.z = pack2bf(d4, d5);
            r.w = pack2bf(d6, d7);
        }
        *(uint4*)&amx[ln][c * 8] = r;
    }
    __syncthreads();

    // ---- phase 2: MFMA GEMM (verified round-3 layout) ----
    int mm = lane & 15, g = lane >> 4;
    int rt = w & 3, ch = w >> 2;
    int r0 = nbase + rt * 16;
    int row = r0 + mm;
    bool rowok = row < NN;

    f32x4 acc[4];
#pragma unroll
    for (int ct = 0; ct < 4; ct++) {
        float bv = bias[ch * 64 + ct * 16 + mm];
        acc[ct] = (f32x4){bv, bv, bv, bv};
    }

    const short* xbs = (const short*)xb;
#pragma unroll
    for (int kc = 0; kc < 8; kc++) {
        int k0 = kc * 32;
        short8 a;
        if (kc < 4) {
            a = (short8){0, 0, 0, 0, 0, 0, 0, 0};
            if (rowok) a = *(const short8*)(xbs + (size_t)row * 128 + k0 + g * 8);
        } else {
            a = *(const short8*)&amx[rt * 16 + mm][(k0 - 128) + g * 8];
        }
#pragma unroll
        for (int ct = 0; ct < 4; ct++) {
            short8 b = *(const short8*)(wt + (size_t)(ch * 64 + ct * 16 + mm) * 256 + k0 + g * 8);
            acc[ct] = __builtin_amdgcn_mfma_f32_16x16x32_bf16(a, b, acc[ct], 0, 0, 0);
        }
    }

#pragma unroll
    for (int ct = 0; ct < 4; ct++) {
#pragma unroll
        for (int i = 0; i < 4; i++) {
            int rr = r0 + g * 4 + i;
            if (rr < NN) out[(size_t)rr * 128 + ch * 64 + ct * 16 + mm] = acc[ct][i];
        }
    }
}

// ---------------- launch ----------------

extern "C" void kernel_launch(void* const* d_in, const int* in_sizes, int n_in,
                              void* d_out, int out_size, void* d_ws, size_t ws_size,
                              hipStream_t stream) {
    const float* x = (const float*)d_in[0];
    const int* ei = (const int*)d_in[1];     // (2, E): [0..E)=src, [E..2E)=dst
    const float* W = (const float*)d_in[2];  // (256, 128) row-major
    const float* bias = (const float*)d_in[3];
    float* out = (float*)d_out;

    // Workspace layout (ints). Total = 4,866,448 ints = 19.47 MB.
    int* wsi = (int*)d_ws;
    int* head = wsi;                                        // 50048 ints
    ull* nxt2 = (ull*)(wsi + 50048);                        // 800000 ull = 1,600,000 ints (8B-aligned)
    unsigned* xb  = (unsigned*)(wsi + 1650048);             // 3,200,000 uints (16B-aligned)
    unsigned short* wt = (unsigned short*)(wsi + 4850048);  // 32768 ush = 16384 ints

    hipMemsetAsync(head, 0xFF, NN * sizeof(int), stream);   // head = -1

    prep3_k<<<PB, 256, 0, stream>>>(ei, x, W, head, nxt2, xb, wt);
    fused_k<<<(NN + 63) / 64, 512, 0, stream>>>(xb, head, nxt2, (const short*)wt,
                                                bias, out);
}